// Round 6
// baseline (208.556 us; speedup 1.0000x reference)
//
#include <hip/hip_runtime.h>

#define HW 16384   // 128*128

typedef __attribute__((ext_vector_type(8))) short short8;
typedef __attribute__((ext_vector_type(16))) float floatx16;

__device__ inline unsigned short f2bf(float f) {
    unsigned u = __builtin_bit_cast(unsigned, f);
    u = (u + 0x7FFFu + ((u >> 16) & 1u)) >> 16;   // RNE
    return (unsigned short)u;
}

// pack two fp32 -> bf16x2 by truncation: one v_perm_b32
__device__ inline unsigned pack_bf_trunc(float lo, float hi) {
    return __builtin_amdgcn_perm(__builtin_bit_cast(unsigned, hi),
                                 __builtin_bit_cast(unsigned, lo), 0x07060302u);
}

// ---------------------------------------------------------------------------
// Cast W q/k/v -> bf16 Wb[320][256]: rows 0-31 q, 32-63 k, 64-319 v.
// ---------------------------------------------------------------------------
__global__ __launch_bounds__(256) void castW_kernel(
    const float* __restrict__ Wq, const float* __restrict__ Wk,
    const float* __restrict__ Wv, unsigned short* __restrict__ Wb)
{
    int idx4 = blockIdx.x * 256 + threadIdx.x;
    int e0 = idx4 * 4;
    int row = e0 >> 8, col = e0 & 255;
    const float* src = (row < 32) ? (Wq + row * 256 + col)
                     : (row < 64) ? (Wk + (row - 32) * 256 + col)
                                  : (Wv + (row - 64) * 256 + col);
    float4 v = *(const float4*)src;
    uint2 pk;
    pk.x = f2bf(v.x) | ((unsigned)f2bf(v.y) << 16);
    pk.y = f2bf(v.z) | ((unsigned)f2bf(v.w) << 16);
    *(uint2*)&Wb[e0] = pk;
}

// ---------------------------------------------------------------------------
// Cast + transpose x: [b][c][p] fp32 -> xt[b][p][c] bf16.  64c x 64p tiles.
// ---------------------------------------------------------------------------
__global__ __launch_bounds__(256) void cast_xt_kernel(
    const float* __restrict__ x, unsigned short* __restrict__ xt)
{
    __shared__ unsigned short T[64][66];
    const int tid = threadIdx.x;
    const int p0 = blockIdx.x * 64;
    const int c0 = blockIdx.y * 64;
    const int b  = blockIdx.z;
    #pragma unroll
    for (int i = 0; i < 4; i++) {
        int e = i * 256 + tid;
        int c = e >> 4, seg = e & 15;
        float4 v = *(const float4*)&x[((b * 256 + c0 + c) << 14) + p0 + seg * 4];
        ((unsigned*)&T[c][seg * 4])[0] = f2bf(v.x) | ((unsigned)f2bf(v.y) << 16);
        ((unsigned*)&T[c][seg * 4])[1] = f2bf(v.z) | ((unsigned)f2bf(v.w) << 16);
    }
    __syncthreads();
    #pragma unroll
    for (int i = 0; i < 2; i++) {
        int e = i * 256 + tid;
        int p = e >> 3, cs = e & 7;
        unsigned short t[8];
        #pragma unroll
        for (int j = 0; j < 8; j++) t[j] = T[cs * 8 + j][p];
        uint4 pk;
        pk.x = t[0] | ((unsigned)t[1] << 16);
        pk.y = t[2] | ((unsigned)t[3] << 16);
        pk.z = t[4] | ((unsigned)t[5] << 16);
        pk.w = t[6] | ((unsigned)t[7] << 16);
        *(uint4*)&xt[(((b << 14) + p0 + p) << 8) + c0 + cs * 8] = pk;
    }
}

// ---------------------------------------------------------------------------
// MFMA projection (unchanged from round 5).
// ---------------------------------------------------------------------------
__global__ __launch_bounds__(256, 3) void proj_mfma_kernel(
    const unsigned short* __restrict__ Wb, const unsigned short* __restrict__ xt,
    const float* __restrict__ bq, const float* __restrict__ bk,
    const float* __restrict__ bv,
    unsigned short* __restrict__ qb, unsigned short* __restrict__ kb,
    unsigned short* __restrict__ vb)
{
    __shared__ __align__(16) unsigned short As[64 * 64];
    __shared__ __align__(16) unsigned short Bs[256 * 64];
    __shared__ float biasS[64];
    const int tid = threadIdx.x;
    const int p0  = blockIdx.x * 256;
    const int oc0 = blockIdx.y * 64;
    const int b   = blockIdx.z;
    const int w = tid >> 6, lr = tid & 31, lh = (tid & 63) >> 5;

    if (tid < 64) biasS[tid] = (oc0 == 0) ? ((tid < 32) ? bq[tid] : bk[tid - 32])
                                          : bv[oc0 - 64 + tid];

    floatx16 z16 = {0,0,0,0,0,0,0,0,0,0,0,0,0,0,0,0};
    floatx16 acc[2][2] = {{z16, z16}, {z16, z16}};
    const int bpx = (b << 14) + p0;

    for (int kc = 0; kc < 256; kc += 64) {
        if (kc) __syncthreads();
        #pragma unroll
        for (int i = 0; i < 2; i++) {
            int e = i * 256 + tid;
            int row = e >> 3, seg = e & 7, cp = seg ^ (row & 7);
            *(uint4*)&As[row * 64 + cp * 8] =
                *(const uint4*)&Wb[(oc0 + row) * 256 + kc + seg * 8];
        }
        #pragma unroll
        for (int i = 0; i < 8; i++) {
            int e = i * 256 + tid;
            int row = e >> 3, seg = e & 7, cp = seg ^ (row & 7);
            *(uint4*)&Bs[row * 64 + cp * 8] =
                *(const uint4*)&xt[((bpx + row) << 8) + kc + seg * 8];
        }
        __syncthreads();
        #pragma unroll
        for (int ks = 0; ks < 4; ks++) {
            int c = 2 * ks + lh;
            int cx = (c ^ (lr & 7)) * 8;
            short8 af0 = *(const short8*)&As[lr * 64 + cx];
            short8 af1 = *(const short8*)&As[(32 + lr) * 64 + cx];
            short8 bf0 = *(const short8*)&Bs[(64 * w + lr) * 64 + cx];
            short8 bf1 = *(const short8*)&Bs[(64 * w + 32 + lr) * 64 + cx];
            acc[0][0] = __builtin_amdgcn_mfma_f32_32x32x16_bf16(af0, bf0, acc[0][0], 0, 0, 0);
            acc[0][1] = __builtin_amdgcn_mfma_f32_32x32x16_bf16(af0, bf1, acc[0][1], 0, 0, 0);
            acc[1][0] = __builtin_amdgcn_mfma_f32_32x32x16_bf16(af1, bf0, acc[1][0], 0, 0, 0);
            acc[1][1] = __builtin_amdgcn_mfma_f32_32x32x16_bf16(af1, bf1, acc[1][1], 0, 0, 0);
        }
    }

    __syncthreads();
    if (oc0 == 0) {
        unsigned short* Cq = Bs;
        #pragma unroll
        for (int i = 0; i < 2; i++) {
            #pragma unroll
            for (int j = 0; j < 2; j++) {
                int px = 64 * w + 32 * j + lr;
                #pragma unroll
                for (int g = 0; g < 4; g++) {
                    float v0 = acc[i][j][4*g+0] + biasS[32*i + 8*g + 4*lh + 0];
                    float v1 = acc[i][j][4*g+1] + biasS[32*i + 8*g + 4*lh + 1];
                    float v2 = acc[i][j][4*g+2] + biasS[32*i + 8*g + 4*lh + 2];
                    float v3 = acc[i][j][4*g+3] + biasS[32*i + 8*g + 4*lh + 3];
                    uint2 u; u.x = pack_bf_trunc(v0, v1); u.y = pack_bf_trunc(v2, v3);
                    int cp = (4 * i + g) ^ (px & 7);
                    *(uint2*)&Cq[px * 64 + cp * 8 + 4 * lh] = u;
                }
            }
        }
        __syncthreads();
        #pragma unroll
        for (int i = 0; i < 8; i++) {
            int px = tid;
            int cp = i ^ (px & 7);
            uint4 val = *(const uint4*)&Cq[px * 64 + cp * 8];
            if (i < 4) *(uint4*)&qb[(unsigned)((b * 4 + i)     * HW + p0 + px) * 8] = val;
            else       *(uint4*)&kb[(unsigned)((b * 4 + i - 4) * HW + p0 + px) * 8] = val;
        }
    } else {
        unsigned short* Cv = Bs;
        #pragma unroll
        for (int i = 0; i < 2; i++) {
            #pragma unroll
            for (int j = 0; j < 2; j++) {
                int px = 64 * w + 32 * j + lr;
                #pragma unroll
                for (int reg = 0; reg < 16; reg++) {
                    int oc = 32 * i + (reg & 3) + 8 * (reg >> 2) + 4 * lh;
                    float v = acc[i][j][reg] + biasS[oc];
                    int cp = (px >> 3) ^ (oc & 31);
                    Cv[oc * 256 + cp * 8 + (px & 7)] =
                        (unsigned short)(__builtin_bit_cast(unsigned, v) >> 16);
                }
            }
        }
        __syncthreads();
        #pragma unroll
        for (int i = 0; i < 8; i++) {   // 64 oc x 32 seg = 2048 uint4
            int u = i * 256 + tid;
            int oc = u >> 5, seg = u & 31;
            int cp = seg ^ (oc & 31);
            uint4 val = *(const uint4*)&Cv[oc * 256 + cp * 8];
            *(uint4*)&vb[(unsigned)(b * 256 + oc0 - 64 + oc) * HW + p0 + seg * 8] = val;
        }
    }
}

// ---------------------------------------------------------------------------
// Transpose q/k NHWC planes (unchanged).
// ---------------------------------------------------------------------------
__global__ __launch_bounds__(256) void tqk_kernel(
    const unsigned short* __restrict__ qb, const unsigned short* __restrict__ kb,
    unsigned short* __restrict__ qt, unsigned short* __restrict__ kt)
{
    __shared__ uint4 t[32][33];
    const int plane = blockIdx.y;
    const int tile  = blockIdx.x;
    const int tx = tile & 3, ty = tile >> 2;
    const uint4* src = (const uint4*)(plane < 16 ? qb : kb) + (plane & 15) * HW;
    uint4*       dst = (uint4*)(plane < 16 ? qt : kt) + (plane & 15) * HW;
    const int c = threadIdx.x & 31, r0 = threadIdx.x >> 5;
    #pragma unroll
    for (int i = 0; i < 4; i++) {
        int r = r0 + i * 8;
        t[r][c] = src[(ty * 32 + r) * 128 + tx * 32 + c];
    }
    __syncthreads();
    #pragma unroll
    for (int i = 0; i < 4; i++) {
        int r = r0 + i * 8;
        dst[(tx * 32 + r) * 128 + ty * 32 + c] = t[c][r];
    }
}

// ---------------------------------------------------------------------------
// Transpose v planes (unchanged).
// ---------------------------------------------------------------------------
__global__ __launch_bounds__(256) void tv_kernel(
    const unsigned short* __restrict__ vb, unsigned short* __restrict__ vt)
{
    __shared__ unsigned short T[64][66];
    const int plane = blockIdx.y;
    const int tile  = blockIdx.x;
    const int tx = tile & 1, ty = tile >> 1;
    const unsigned* src = (const unsigned*)(vb + plane * HW);
    unsigned*       dst = (unsigned*)(vt + plane * HW);
    const int tid = threadIdx.x;
    #pragma unroll
    for (int i = 0; i < 8; i++) {
        int e = i * 256 + tid;
        int r = e >> 5, cp = e & 31;
        *(unsigned*)&T[r][2 * cp] = src[(ty * 64 + r) * 64 + tx * 32 + cp];
    }
    __syncthreads();
    #pragma unroll
    for (int i = 0; i < 8; i++) {
        int e = i * 256 + tid;
        int c = e >> 5, rp = e & 31;
        unsigned lo = T[2 * rp][c], hi = T[2 * rp + 1][c];
        dst[(tx * 64 + c) * 64 + ty * 32 + rp] = lo | (hi << 16);
    }
}

// ---------------------------------------------------------------------------
// MFMA attention v3: wave-local softmax, P in registers, ONE barrier.
// Each wave owns 32 queries x all 128 keys. E: A=K-frag(4 key-blocks),
// B=own Q-frag. C-layout: col=query(lane&31), keys in regs (4lh split).
// P kept UNNORMALIZED bf16-packed in regs; B-frag built per 16-key chunk via
// one uint2 shfl_xor(lane^32) + cndmask (keys 16ks+8lh+j <- group 2h2+lh of
// both halves). Normalization folded into O: o*=(l1/l0) between stages,
// o*=1/l1 at end -> O0/l0 + O1/l1 exactly. Vs double-buffered (32 KB LDS).
// ---------------------------------------------------------------------------
__global__ __launch_bounds__(256, 4) void attn_kernel(
    const unsigned short* __restrict__ qb, const unsigned short* __restrict__ kb,
    const unsigned short* __restrict__ vb,
    const unsigned short* __restrict__ qt, const unsigned short* __restrict__ kt,
    const unsigned short* __restrict__ vt,
    const float* __restrict__ xin, const float* __restrict__ gamma,
    float* __restrict__ out)
{
    __shared__ __align__(16) unsigned short Vs[2][64 * 128];   // [st][ch][key], chunk^=(ch&15)

    const int tid = threadIdx.x;
    const int y = blockIdx.x, bh = blockIdx.y;
    const int w = tid >> 6, l = tid & 63, lr = l & 31;
    const bool lhi = (l & 32) != 0;
    const float L2E = 1.4426950408889634f;

    floatx16 z16 = {0,0,0,0,0,0,0,0,0,0,0,0,0,0,0,0};
    floatx16 o0 = z16, o1 = z16;
    short8 z8 = {0,0,0,0,0,0,0,0};

    // ---- stage both V buffers up front (single barrier covers both) ----
    #pragma unroll
    for (int st = 0; st < 2; st++) {
        const unsigned short* vsrc = st ? vt : vb;
        #pragma unroll
        for (int i = 0; i < 4; i++) {
            int e = i * 256 + tid;
            int ch = e >> 4, sg = e & 15;
            int sgp = sg ^ (ch & 15);
            *(uint4*)&Vs[st][ch * 128 + sgp * 8] =
                *(const uint4*)(vsrc + (bh * 64 + ch) * HW + y * 128 + sg * 8);
        }
    }

    uint2 pk[4][4];   // [key-block][group] packed unnormalized P (bf16x2 pairs)

    // ===== E stage 0 =====
    const unsigned short* q0 = qb + (bh * 128 + y) * 1024;
    const unsigned short* k0 = kb + (bh * 128 + y) * 1024;
    float l0 = 0.f;
    {
        short8 bf = z8, af[4] = {z8, z8, z8, z8};
        if (!lhi) {
            bf = *(const short8*)(q0 + (32 * w + lr) * 8);
            #pragma unroll
            for (int kblk = 0; kblk < 4; kblk++)
                af[kblk] = *(const short8*)(k0 + (32 * kblk + lr) * 8);
        }
        #pragma unroll
        for (int kblk = 0; kblk < 4; kblk++) {
            floatx16 et = __builtin_amdgcn_mfma_f32_32x32x16_bf16(af[kblk], bf, z16, 0, 0, 0);
            #pragma unroll
            for (int g = 0; g < 4; g++) {
                float p0 = exp2f(et[4*g+0] * L2E);
                float p1 = exp2f(et[4*g+1] * L2E);
                float p2 = exp2f(et[4*g+2] * L2E);
                float p3 = exp2f(et[4*g+3] * L2E);
                l0 += (p0 + p1) + (p2 + p3);
                pk[kblk][g].x = pack_bf_trunc(p0, p1);
                pk[kblk][g].y = pack_bf_trunc(p2, p3);
            }
        }
    }
    l0 += __shfl_xor(l0, 32);

    __syncthreads();   // the ONLY barrier: Vs (both buffers) ready

    // ===== PV stage 0 (unnormalized) =====
    #pragma unroll
    for (int ks = 0; ks < 8; ks++) {
        int kblk = ks >> 1, h2 = ks & 1;
        uint2 a = pk[kblk][2 * h2], b2 = pk[kblk][2 * h2 + 1];
        unsigned ownx = lhi ? b2.x : a.x,  owny = lhi ? b2.y : a.y;
        unsigned sndx = lhi ? a.x  : b2.x, sndy = lhi ? a.y  : b2.y;
        unsigned rcx = (unsigned)__shfl_xor((int)sndx, 32);
        unsigned rcy = (unsigned)__shfl_xor((int)sndy, 32);
        uint4 uu;
        uu.x = lhi ? rcx : ownx;  uu.y = lhi ? rcy : owny;
        uu.z = lhi ? ownx : rcx;  uu.w = lhi ? owny : rcy;
        short8 pf = __builtin_bit_cast(short8, uu);
        int cp = ((2 * ks + (lhi ? 1 : 0)) ^ (lr & 15)) * 8;
        short8 v0 = *(const short8*)&Vs[0][lr * 128 + cp];
        short8 v1 = *(const short8*)&Vs[0][(32 + lr) * 128 + cp];
        o0 = __builtin_amdgcn_mfma_f32_32x32x16_bf16(v0, pf, o0, 0, 0, 0);
        o1 = __builtin_amdgcn_mfma_f32_32x32x16_bf16(v1, pf, o1, 0, 0, 0);
    }

    // ===== E stage 1 =====
    const unsigned short* q1 = qt + (bh * 128 + y) * 1024;
    const unsigned short* k1 = kt + (bh * 128 + y) * 1024;
    float l1 = 0.f;
    {
        short8 bf = z8, af[4] = {z8, z8, z8, z8};
        if (!lhi) {
            bf = *(const short8*)(q1 + (32 * w + lr) * 8);
            #pragma unroll
            for (int kblk = 0; kblk < 4; kblk++)
                af[kblk] = *(const short8*)(k1 + (32 * kblk + lr) * 8);
        }
        #pragma unroll
        for (int kblk = 0; kblk < 4; kblk++) {
            floatx16 et = __builtin_amdgcn_mfma_f32_32x32x16_bf16(af[kblk], bf, z16, 0, 0, 0);
            #pragma unroll
            for (int g = 0; g < 4; g++) {
                float p0 = exp2f(et[4*g+0] * L2E);
                float p1 = exp2f(et[4*g+1] * L2E);
                float p2 = exp2f(et[4*g+2] * L2E);
                float p3 = exp2f(et[4*g+3] * L2E);
                l1 += (p0 + p1) + (p2 + p3);
                pk[kblk][g].x = pack_bf_trunc(p0, p1);
                pk[kblk][g].y = pack_bf_trunc(p2, p3);
            }
        }
    }
    l1 += __shfl_xor(l1, 32);

    // rescale stage-0 contribution: o = O0 * (l1/l0)
    float s01 = l1 / l0;
    #pragma unroll
    for (int r = 0; r < 16; r++) { o0[r] *= s01; o1[r] *= s01; }

    // ===== PV stage 1 =====
    #pragma unroll
    for (int ks = 0; ks < 8; ks++) {
        int kblk = ks >> 1, h2 = ks & 1;
        uint2 a = pk[kblk][2 * h2], b2 = pk[kblk][2 * h2 + 1];
        unsigned ownx = lhi ? b2.x : a.x,  owny = lhi ? b2.y : a.y;
        unsigned sndx = lhi ? a.x  : b2.x, sndy = lhi ? a.y  : b2.y;
        unsigned rcx = (unsigned)__shfl_xor((int)sndx, 32);
        unsigned rcy = (unsigned)__shfl_xor((int)sndy, 32);
        uint4 uu;
        uu.x = lhi ? rcx : ownx;  uu.y = lhi ? rcy : owny;
        uu.z = lhi ? ownx : rcx;  uu.w = lhi ? owny : rcy;
        short8 pf = __builtin_bit_cast(short8, uu);
        int cp = ((2 * ks + (lhi ? 1 : 0)) ^ (lr & 15)) * 8;
        short8 v0 = *(const short8*)&Vs[1][lr * 128 + cp];
        short8 v1 = *(const short8*)&Vs[1][(32 + lr) * 128 + cp];
        o0 = __builtin_amdgcn_mfma_f32_32x32x16_bf16(v0, pf, o0, 0, 0, 0);
        o1 = __builtin_amdgcn_mfma_f32_32x32x16_bf16(v1, pf, o1, 0, 0, 0);
    }

    // ===== epilogue: out = gamma*(o/l1) + x  (o = O0*l1/l0 + O1) =====
    const float c = gamma[0] / l1;
    const int lh = lhi ? 1 : 0;
    const int xq = 32 * w + lr;
    #pragma unroll
    for (int reg = 0; reg < 16; reg++) {
        int ch = (reg & 3) + 8 * (reg >> 2) + 4 * lh;
        int idx0 = (bh * 64 + ch) * HW + y * 128 + xq;
        int idx1 = (bh * 64 + 32 + ch) * HW + y * 128 + xq;
        out[idx0] = c * o0[reg] + xin[idx0];
        out[idx1] = c * o1[reg] + xin[idx1];
    }
}

extern "C" void kernel_launch(void* const* d_in, const int* in_sizes, int n_in,
                              void* d_out, int out_size, void* d_ws, size_t ws_size,
                              hipStream_t stream) {
    const float* x     = (const float*)d_in[0];
    const float* Wq    = (const float*)d_in[1];
    const float* bq    = (const float*)d_in[2];
    const float* Wk    = (const float*)d_in[3];
    const float* bk    = (const float*)d_in[4];
    const float* Wv    = (const float*)d_in[5];
    const float* bv    = (const float*)d_in[6];
    const float* gamma = (const float*)d_in[7];
    float* out = (float*)d_out;

    unsigned short* Wb   = (unsigned short*)d_ws;
    unsigned short* qb16 = Wb + 320 * 256;
    unsigned short* kb16 = qb16 + 16 * HW * 8;
    unsigned short* qt16 = kb16 + 16 * HW * 8;
    unsigned short* kt16 = qt16 + 16 * HW * 8;
    unsigned short* vb16 = kt16 + 16 * HW * 8;
    unsigned short* vt16 = vb16 + 1024 * HW;
    // xt (bf16 x transposed) lives in d_out: consumed by proj before attn writes.
    unsigned short* xt = (unsigned short*)d_out;

    castW_kernel<<<dim3(80), 256, 0, stream>>>(Wq, Wk, Wv, Wb);
    cast_xt_kernel<<<dim3(256, 4, 4), 256, 0, stream>>>(x, xt);
    proj_mfma_kernel<<<dim3(64, 5, 4), 256, 0, stream>>>(Wb, xt, bq, bk, bv, qb16, kb16, vb16);
    tqk_kernel<<<dim3(16, 32), 256, 0, stream>>>(qb16, kb16, qt16, kt16);
    tv_kernel<<<dim3(4, 1024), 256, 0, stream>>>(vb16, vt16);
    attn_kernel<<<dim3(128, 16), 256, 0, stream>>>(qb16, kb16, vb16, qt16, kt16, vt16, x, gamma, out);
}